// Round 4
// baseline (492.156 us; speedup 1.0000x reference)
//
#include <hip/hip_runtime.h>
#include <hip/hip_bf16.h>
#include <math.h>
#include <stdint.h>

typedef unsigned short u16;
typedef __attribute__((ext_vector_type(8))) short bfrag;      // 8 bf16 = 4 VGPR
typedef __attribute__((ext_vector_type(4))) float f32x4;
typedef __attribute__((ext_vector_type(8))) unsigned short u16x8;
typedef __attribute__((ext_vector_type(4))) unsigned short u16x4;

#define BB 16
#define CC 128
#define HH 128
#define WW 128
#define GG 32
#define EPSV 1e-5f
#define NEG 0.1f

__device__ __forceinline__ float bf2f(u16 u) {
    unsigned int x = ((unsigned int)u) << 16;
    return __builtin_bit_cast(float, x);
}
__device__ __forceinline__ u16 f2bf(float f) {   // RNE
    unsigned int x = __builtin_bit_cast(unsigned int, f);
    unsigned int r = x + 0x7fffu + ((x >> 16) & 1u);
    return (u16)(r >> 16);
}
__device__ __forceinline__ void gload_lds16(const void* g, void* l) {
    __builtin_amdgcn_global_load_lds(
        (const __attribute__((address_space(1))) void*)g,
        (__attribute__((address_space(3))) void*)l, 16, 0, 0);
}

// ---------------- GroupNorm statistics: one block per (b,g) ----------------
__global__ __launch_bounds__(256)
void gn_stats_kernel(const float* __restrict__ x, float* __restrict__ stats) {
    const int bg = blockIdx.x;                 // 0..511
    const float* base = x + (size_t)bg * 65536;
    float s1 = 0.f, s2 = 0.f;
    for (int i = threadIdx.x; i < 16384; i += 256) {
        float4 v = *(const float4*)&base[i * 4];
        s1 += v.x + v.y + v.z + v.w;
        s2 += v.x * v.x + v.y * v.y + v.z * v.z + v.w * v.w;
    }
    #pragma unroll
    for (int off = 32; off > 0; off >>= 1) {
        s1 += __shfl_down(s1, off);
        s2 += __shfl_down(s2, off);
    }
    __shared__ float rs[8];
    const int wid = threadIdx.x >> 6, lane = threadIdx.x & 63;
    if (lane == 0) { rs[wid * 2] = s1; rs[wid * 2 + 1] = s2; }
    __syncthreads();
    if (threadIdx.x == 0) {
        s1 = rs[0] + rs[2] + rs[4] + rs[6];
        s2 = rs[1] + rs[3] + rs[5] + rs[7];
        float mean = s1 * (1.f / 65536.f);
        float var  = s2 * (1.f / 65536.f) - mean * mean;
        stats[2 * bg]     = mean;
        stats[2 * bg + 1] = rsqrtf(var + EPSV);
    }
}

// ------ weight fp32 [co][ci][9] -> bf16 [tap][chunk(4)][co(128)][g(4)][8] ---
__global__ __launch_bounds__(256)
void wconv_kernel(const float* __restrict__ w1, const float* __restrict__ w2,
                  u16* __restrict__ w1t, u16* __restrict__ w2t) {
    int idx = blockIdx.x * 256 + threadIdx.x;      // 147456
    if (idx < 147456) {
        int e  = idx & 7;
        int g  = (idx >> 3) & 3;
        int co = (idx >> 5) & 127;
        int ck = (idx >> 12) & 3;
        int t  = idx >> 14;
        int src = (co * 128 + (ck * 32 + g * 8 + e)) * 9 + t;
        w1t[idx] = f2bf(w1[src]);
        w2t[idx] = f2bf(w2[src]);
    }
}

// ------- small FCs: biastot = te@nfw^T + nf_b + conv1_b ; tmp1 = leaky(kv@kW1^T)
__global__ __launch_bounds__(256)
void small1_kernel(const float* __restrict__ te, const float* __restrict__ nfw,
                   const float* __restrict__ nfbias, const float* __restrict__ c1b,
                   const float* __restrict__ kv, const float* __restrict__ kw1,
                   float* __restrict__ biastot, float* __restrict__ tmp1) {
    const int idx = blockIdx.x * 256 + threadIdx.x;
    if (idx < 1024) {                       // tmp1: (16,64)
        const int b = idx >> 6, j = idx & 63;
        float s = 0.f;
        for (int e = 0; e < 64; ++e) s += kv[b * 64 + e] * kw1[j * 64 + e];
        tmp1[idx] = s >= 0.f ? s : NEG * s;
    } else if (idx < 1024 + 2048) {         // biastot: (16,128)
        const int t = idx - 1024;
        const int b = t >> 7, c = t & 127;
        float s = nfbias[c] + c1b[c];
        for (int e = 0; e < 128; ++e) s += te[b * 128 + e] * nfw[c * 128 + e];
        biastot[t] = s;
    }
}

__global__ __launch_bounds__(256)
void small2_kernel(const float* __restrict__ tmp1, const float* __restrict__ kw2,
                   float* __restrict__ kern) {
    const int idx = blockIdx.x * 256 + threadIdx.x;    // 18432
    if (idx < BB * CC * 9) {
        const int b = idx / 1152, rc = idx % 1152;
        float s = 0.f;
        for (int e = 0; e < 64; ++e) s += tmp1[b * 64 + e] * kw2[rc * 64 + e];
        kern[idx] = s;
    }
}

// ------- GroupNorm apply + Swish, NCHW fp32 -> NHWC bf16 (LDS transpose) ----
__global__ __launch_bounds__(256)
void gn_apply_kernel(const float* __restrict__ x, const float* __restrict__ gamma,
                     const float* __restrict__ beta, const float* __restrict__ stats,
                     u16* __restrict__ hact) {
    __shared__ u16 s_t[128 * 128];
    const int tid = threadIdx.x;
    const int y = blockIdx.x & 127, b = blockIdx.x >> 7;
    #pragma unroll
    for (int i = 0; i < 16; ++i) {
        int unit = (i << 8) + tid;              // (c, x-quad)
        int c = unit >> 5, xq = unit & 31, xx = xq * 4;
        float4 v = *(const float4*)&x[(((size_t)b * 128 + c) * 128 + y) * 128 + xx];
        int gi = b * 32 + (c >> 2);
        float mean = stats[2 * gi], rstd = stats[2 * gi + 1];
        float ga = gamma[c] * rstd, be = beta[c] - mean * ga;
        float a0 = v.x * ga + be, a1 = v.y * ga + be, a2 = v.z * ga + be, a3 = v.w * ga + be;
        a0 = a0 / (1.f + __expf(-a0)); a1 = a1 / (1.f + __expf(-a1));
        a2 = a2 / (1.f + __expf(-a2)); a3 = a3 / (1.f + __expf(-a3));
        int cs = c ^ ((xq & 15) << 3);          // bank swizzle, keeps 8-groups intact
        s_t[(xx + 0) * 128 + cs] = f2bf(a0);
        s_t[(xx + 1) * 128 + cs] = f2bf(a1);
        s_t[(xx + 2) * 128 + cs] = f2bf(a2);
        s_t[(xx + 3) * 128 + cs] = f2bf(a3);
    }
    __syncthreads();
    #pragma unroll
    for (int i = 0; i < 8; ++i) {
        int unit = (i << 8) + tid;              // (x, c-group)
        int xx = unit >> 4, c0 = (unit & 15) * 8;
        int c0s = c0 ^ (((xx >> 2) & 15) << 3);
        u16x8 v = *(const u16x8*)&s_t[xx * 128 + c0s];
        *(u16x8*)&hact[((((size_t)b * 128 + y) * 128 + xx) * 128) + c0] = v;
    }
}

// ---------------- MFMA implicit-GEMM 3x3 conv, 128->128, SAME --------------
// act: NHWC bf16. wt: [tap][chunk][co][g][8] bf16.
// Per chunk: ALL 9 taps' A-frags preloaded to VGPRs (36 independent global
// loads, one latency), act double-buffered in LDS, 144 MFMA between barriers.
// FINAL=0: outh(NHWC bf16) = conv(act) + biastot[b][co]
// FINAL=1: outf(NCHW fp32) += conv(act) + bias[co]
template <int FINAL>
__global__ __launch_bounds__(256, 2)
void conv_mfma_kernel(const u16* __restrict__ act, const u16* __restrict__ wt,
                      const float* __restrict__ bias,
                      float* __restrict__ outf, u16* __restrict__ outh) {
    __shared__ __align__(16) u16 s_in[2][5760];   // [buf][cik(4)][pos(180)][8] = 23 KB

    const int tid = threadIdx.x;
    const int lane = tid & 63, wid = tid >> 6;
    const int wm = wid >> 1, wn = wid & 1;
    const int l15 = lane & 15, l4 = lane >> 4;

    const int bid = blockIdx.x;                // 16b x 16ty x 8tx
    const int tx = bid & 7, ty = (bid >> 3) & 15, b = bid >> 7;
    const int x0 = tx * 16, y0 = ty * 8;
    const bool interior = (tx > 0) && (tx < 7) && (ty > 0) && (ty < 15);
    const size_t actbase = (size_t)b * (128 * 128 * 128);

    f32x4 acc[4][4];
    #pragma unroll
    for (int mi = 0; mi < 4; ++mi)
        #pragma unroll
        for (int nj = 0; nj < 4; ++nj) acc[mi][nj] = (f32x4)(0.f);

    auto stage_in = [&](int buf, int ci0) {
        #pragma unroll
        for (int r = 0; r < 3; ++r) {
            int L = r * 256 + tid;
            if (L < 720) {
                int cik = L / 180, rem = L % 180;
                int yy = rem / 18, xx = rem - yy * 18;
                int gy = y0 + yy - 1, gx = x0 + xx - 1;
                const u16* src = act + actbase + (((size_t)gy * 128 + gx) * 128 + ci0 + cik * 8);
                if (interior) {
                    u16* dst = &s_in[buf][(size_t)(r * 256 + ((tid >> 6) << 6)) * 8];
                    gload_lds16(src, dst);
                } else {
                    u16x8 v = (u16x8)(u16)0;
                    if ((unsigned)gy < 128u && (unsigned)gx < 128u) v = *(const u16x8*)src;
                    *(u16x8*)&s_in[buf][(size_t)L * 8] = v;
                }
            }
        }
    };

    stage_in(0, 0);
    __syncthreads();

    // per-thread invariant offsets
    const int bbase = (l4 * 180 + (wn * 4) * 18 + l15) * 8;    // u16 index into s_in[buf]
    const u16* wlane = wt + ((size_t)(wm * 64 + l15)) * 32 + l4 * 8;

    int cur = 0;
    for (int chunk = 0; chunk < 4; ++chunk) {
        // ---- A: preload all 9 taps of this chunk into registers (36 loads) ----
        bfrag aR[9][4];
        #pragma unroll
        for (int t = 0; t < 9; ++t) {
            const u16* wp = wlane + (size_t)(t * 4 + chunk) * 4096;
            aR[t][0] = *(const bfrag*)(wp);
            aR[t][1] = *(const bfrag*)(wp + 512);
            aR[t][2] = *(const bfrag*)(wp + 1024);
            aR[t][3] = *(const bfrag*)(wp + 1536);
        }
        // act prefetch for next chunk (issued after A-loads: never blocks them)
        if (chunk < 3) stage_in(cur ^ 1, (chunk + 1) * 32);

        const u16* sb = &s_in[cur][0];
        #pragma unroll
        for (int tap = 0; tap < 9; ++tap) {
            const int dy = tap / 3, dx = tap - dy * 3;
            const int bo = bbase + (dy * 18 + dx) * 8;
            bfrag b0 = *(const bfrag*)&sb[bo];
            bfrag b1 = *(const bfrag*)&sb[bo + 144];
            bfrag b2 = *(const bfrag*)&sb[bo + 288];
            bfrag b3 = *(const bfrag*)&sb[bo + 432];

            acc[0][0] = __builtin_amdgcn_mfma_f32_16x16x32_bf16(aR[tap][0], b0, acc[0][0], 0, 0, 0);
            acc[0][1] = __builtin_amdgcn_mfma_f32_16x16x32_bf16(aR[tap][0], b1, acc[0][1], 0, 0, 0);
            acc[0][2] = __builtin_amdgcn_mfma_f32_16x16x32_bf16(aR[tap][0], b2, acc[0][2], 0, 0, 0);
            acc[0][3] = __builtin_amdgcn_mfma_f32_16x16x32_bf16(aR[tap][0], b3, acc[0][3], 0, 0, 0);
            acc[1][0] = __builtin_amdgcn_mfma_f32_16x16x32_bf16(aR[tap][1], b0, acc[1][0], 0, 0, 0);
            acc[1][1] = __builtin_amdgcn_mfma_f32_16x16x32_bf16(aR[tap][1], b1, acc[1][1], 0, 0, 0);
            acc[1][2] = __builtin_amdgcn_mfma_f32_16x16x32_bf16(aR[tap][1], b2, acc[1][2], 0, 0, 0);
            acc[1][3] = __builtin_amdgcn_mfma_f32_16x16x32_bf16(aR[tap][1], b3, acc[1][3], 0, 0, 0);
            acc[2][0] = __builtin_amdgcn_mfma_f32_16x16x32_bf16(aR[tap][2], b0, acc[2][0], 0, 0, 0);
            acc[2][1] = __builtin_amdgcn_mfma_f32_16x16x32_bf16(aR[tap][2], b1, acc[2][1], 0, 0, 0);
            acc[2][2] = __builtin_amdgcn_mfma_f32_16x16x32_bf16(aR[tap][2], b2, acc[2][2], 0, 0, 0);
            acc[2][3] = __builtin_amdgcn_mfma_f32_16x16x32_bf16(aR[tap][2], b3, acc[2][3], 0, 0, 0);
            acc[3][0] = __builtin_amdgcn_mfma_f32_16x16x32_bf16(aR[tap][3], b0, acc[3][0], 0, 0, 0);
            acc[3][1] = __builtin_amdgcn_mfma_f32_16x16x32_bf16(aR[tap][3], b1, acc[3][1], 0, 0, 0);
            acc[3][2] = __builtin_amdgcn_mfma_f32_16x16x32_bf16(aR[tap][3], b2, acc[3][2], 0, 0, 0);
            acc[3][3] = __builtin_amdgcn_mfma_f32_16x16x32_bf16(aR[tap][3], b3, acc[3][3], 0, 0, 0);
        }
        __syncthreads();     // drains stage_in prefetch; all readers of cur done
        cur ^= 1;
    }

    // ---- epilogue ----
    if (!FINAL) {
        const float* bb = bias + b * 128;
        #pragma unroll
        for (int mi = 0; mi < 4; ++mi) {
            const int cb = wm * 64 + mi * 16 + l4 * 4;
            float4 bv4 = *(const float4*)&bb[cb];
            #pragma unroll
            for (int nj = 0; nj < 4; ++nj) {
                int y = y0 + wn * 4 + nj, xx = x0 + l15;
                u16x4 p;
                p[0] = f2bf(acc[mi][nj][0] + bv4.x);
                p[1] = f2bf(acc[mi][nj][1] + bv4.y);
                p[2] = f2bf(acc[mi][nj][2] + bv4.z);
                p[3] = f2bf(acc[mi][nj][3] + bv4.w);
                *(u16x4*)&outh[((((size_t)b * 128 + y) * 128 + xx) * 128) + cb] = p;
            }
        }
    } else {
        #pragma unroll
        for (int mi = 0; mi < 4; ++mi) {
            const int cb = wm * 64 + mi * 16 + l4 * 4;
            float4 bv4 = *(const float4*)&bias[cb];
            #pragma unroll
            for (int nj = 0; nj < 4; ++nj) {
                int y = y0 + wn * 4 + nj, xx = x0 + l15;
                size_t obase = (((size_t)b * 128 + cb) * 128 + y) * 128 + xx;
                outf[obase]           += acc[mi][nj][0] + bv4.x;
                outf[obase + 16384]   += acc[mi][nj][1] + bv4.y;
                outf[obase + 32768]   += acc[mi][nj][2] + bv4.z;
                outf[obase + 49152]   += acc[mi][nj][3] + bv4.w;
            }
        }
    }
}

// ------- dynamic depthwise 3x3 + leaky + x residual -> out NCHW fp32 -------
__global__ __launch_bounds__(256)
void dw_kernel(const u16* __restrict__ hbuf, const float* __restrict__ kern,
               const float* __restrict__ xres, float* __restrict__ outf) {
    __shared__ float s_o[128][129];
    const int tid = threadIdx.x;
    const int y = blockIdx.x & 127, b = blockIdx.x >> 7;
    const int c0 = (tid & 15) * 8;

    float kreg[72];
    {
        const float* kp = kern + ((size_t)b * 128 + c0) * 9;
        #pragma unroll
        for (int t = 0; t < 18; ++t)
            *(float4*)&kreg[t * 4] = *(const float4*)&kp[t * 4];
    }

    #pragma unroll
    for (int i = 0; i < 8; ++i) {
        int u = (i << 8) + tid;
        int xx = u >> 4;
        float a8[8];
        #pragma unroll
        for (int e = 0; e < 8; ++e) a8[e] = 0.f;
        #pragma unroll
        for (int dy = 0; dy < 3; ++dy) {
            int gy = y + dy - 1;
            if ((unsigned)gy >= 128u) continue;
            #pragma unroll
            for (int dx = 0; dx < 3; ++dx) {
                int gx = xx + dx - 1;
                if ((unsigned)gx >= 128u) continue;
                u16x8 h = *(const u16x8*)&hbuf[(((size_t)b * 128 + gy) * 128 + gx) * 128 + c0];
                #pragma unroll
                for (int e = 0; e < 8; ++e)
                    a8[e] += bf2f(h[e]) * kreg[e * 9 + dy * 3 + dx];
            }
        }
        #pragma unroll
        for (int e = 0; e < 8; ++e) {
            float v = a8[e];
            s_o[c0 + e][xx] = v >= 0.f ? v : NEG * v;
        }
    }
    __syncthreads();
    #pragma unroll
    for (int i = 0; i < 16; ++i) {
        int unit = (i << 8) + tid;          // (c, x-quad)
        int c = unit >> 5, x4 = (unit & 31) * 4;
        float4 v = *(const float4*)&s_o[c][x4];
        size_t gi = (((size_t)b * 128 + c) * 128 + y) * 128 + x4;
        float4 xr = *(const float4*)&xres[gi];
        v.x += xr.x; v.y += xr.y; v.z += xr.z; v.w += xr.w;
        *(float4*)&outf[gi] = v;
    }
}

extern "C" void kernel_launch(void* const* d_in, const int* in_sizes, int n_in,
                              void* d_out, int out_size, void* d_ws, size_t ws_size,
                              hipStream_t stream) {
    const float* x        = (const float*)d_in[0];
    const float* te       = (const float*)d_in[1];
    const float* kv       = (const float*)d_in[2];
    const float* gn1_g    = (const float*)d_in[3];
    const float* gn1_b    = (const float*)d_in[4];
    const float* conv1_w  = (const float*)d_in[5];
    const float* conv1_b  = (const float*)d_in[6];
    const float* nf_w     = (const float*)d_in[7];
    const float* nf_b     = (const float*)d_in[8];
    const float* kW1      = (const float*)d_in[9];
    const float* kW2      = (const float*)d_in[10];
    const float* daconv_w = (const float*)d_in[11];
    const float* daconv_b = (const float*)d_in[12];

    float* out = (float*)d_out;

    // workspace (alive across the final kernels): kern, w2t, hbuf
    float* kern  = (float*)d_ws;                         // 18432 f32
    u16*   w2t   = (u16*)(kern + 18432);                 // 147456 u16
    u16*   hbuf  = (u16*)(kern + 92160);                 // 33.5M u16 (67 MB)

    // temps dead before dw_kernel overwrite of d_out: live in d_out upper half
    float* up      = out + 16777216;
    float* stats   = up;                                 // 1024
    float* biastot = up + 1024;                          // 2048
    float* tmp1    = up + 3072;                          // 1024
    u16*   w1t     = (u16*)(up + 4096);                  // 147456 u16
    u16*   hact    = (u16*)out;                          // lower half of d_out

    gn_stats_kernel<<<dim3(512), dim3(256), 0, stream>>>(x, stats);
    wconv_kernel<<<dim3(576), dim3(256), 0, stream>>>(conv1_w, daconv_w, w1t, w2t);
    small1_kernel<<<dim3(12), dim3(256), 0, stream>>>(te, nf_w, nf_b, conv1_b, kv, kW1,
                                                      biastot, tmp1);
    small2_kernel<<<dim3(72), dim3(256), 0, stream>>>(tmp1, kW2, kern);
    gn_apply_kernel<<<dim3(2048), dim3(256), 0, stream>>>(x, gn1_g, gn1_b, stats, hact);

    // conv1: hbuf = conv(hact) + biastot   (NHWC bf16)
    conv_mfma_kernel<0><<<dim3(2048), dim3(256), 0, stream>>>(hact, w1t, biastot, nullptr, hbuf);
    // dw: out = leaky(depthwise(hbuf, kern)) + x   (NCHW fp32, overwrites all of d_out)
    dw_kernel<<<dim3(2048), dim3(256), 0, stream>>>(hbuf, kern, x, out);
    // conv2: out += conv(hbuf) + daconv_b
    conv_mfma_kernel<1><<<dim3(2048), dim3(256), 0, stream>>>(hbuf, w2t, daconv_b, out, nullptr);
}

// Round 5
// 433.366 us; speedup vs baseline: 1.1357x; 1.1357x over previous
//
#include <hip/hip_runtime.h>
#include <hip/hip_bf16.h>
#include <math.h>
#include <stdint.h>

typedef unsigned short u16;
typedef __attribute__((ext_vector_type(8))) short bfrag;      // 8 bf16 = 4 VGPR
typedef __attribute__((ext_vector_type(4))) float f32x4;
typedef __attribute__((ext_vector_type(8))) unsigned short u16x8;
typedef __attribute__((ext_vector_type(4))) unsigned short u16x4;

#define BB 16
#define CC 128
#define HH 128
#define WW 128
#define GG 32
#define EPSV 1e-5f
#define NEG 0.1f

__device__ __forceinline__ float bf2f(u16 u) {
    unsigned int x = ((unsigned int)u) << 16;
    return __builtin_bit_cast(float, x);
}
__device__ __forceinline__ u16 f2bf(float f) {   // RNE
    unsigned int x = __builtin_bit_cast(unsigned int, f);
    unsigned int r = x + 0x7fffu + ((x >> 16) & 1u);
    return (u16)(r >> 16);
}
__device__ __forceinline__ void gload_lds16(const void* g, void* l) {
    __builtin_amdgcn_global_load_lds(
        (const __attribute__((address_space(1))) void*)g,
        (__attribute__((address_space(3))) void*)l, 16, 0, 0);
}

// ---------------- GroupNorm statistics: one block per (b,g) ----------------
__global__ __launch_bounds__(256)
void gn_stats_kernel(const float* __restrict__ x, float* __restrict__ stats) {
    const int bg = blockIdx.x;                 // 0..511
    const float* base = x + (size_t)bg * 65536;
    float s1 = 0.f, s2 = 0.f;
    for (int i = threadIdx.x; i < 16384; i += 256) {
        float4 v = *(const float4*)&base[i * 4];
        s1 += v.x + v.y + v.z + v.w;
        s2 += v.x * v.x + v.y * v.y + v.z * v.z + v.w * v.w;
    }
    #pragma unroll
    for (int off = 32; off > 0; off >>= 1) {
        s1 += __shfl_down(s1, off);
        s2 += __shfl_down(s2, off);
    }
    __shared__ float rs[8];
    const int wid = threadIdx.x >> 6, lane = threadIdx.x & 63;
    if (lane == 0) { rs[wid * 2] = s1; rs[wid * 2 + 1] = s2; }
    __syncthreads();
    if (threadIdx.x == 0) {
        s1 = rs[0] + rs[2] + rs[4] + rs[6];
        s2 = rs[1] + rs[3] + rs[5] + rs[7];
        float mean = s1 * (1.f / 65536.f);
        float var  = s2 * (1.f / 65536.f) - mean * mean;
        stats[2 * bg]     = mean;
        stats[2 * bg + 1] = rsqrtf(var + EPSV);
    }
}

// --- weight fp32 [co][ci][9] -> bf16 [tap(9)][chunk(4)][g(4)][co(128)][8] ---
// Matches the LDS A-layout so stage_w is perfectly coalesced 16B/lane.
__global__ __launch_bounds__(256)
void wconv_kernel(const float* __restrict__ w1, const float* __restrict__ w2,
                  u16* __restrict__ w1t, u16* __restrict__ w2t) {
    int idx = blockIdx.x * 256 + threadIdx.x;      // 147456
    if (idx < 147456) {
        int e  = idx & 7;
        int co = (idx >> 3) & 127;
        int g  = (idx >> 10) & 3;
        int ck = (idx >> 12) & 3;
        int t  = idx >> 14;
        int src = (co * 128 + (ck * 32 + g * 8 + e)) * 9 + t;
        w1t[idx] = f2bf(w1[src]);
        w2t[idx] = f2bf(w2[src]);
    }
}

// ------- small FCs: biastot = te@nfw^T + nf_b + conv1_b ; tmp1 = leaky(kv@kW1^T)
__global__ __launch_bounds__(256)
void small1_kernel(const float* __restrict__ te, const float* __restrict__ nfw,
                   const float* __restrict__ nfbias, const float* __restrict__ c1b,
                   const float* __restrict__ kv, const float* __restrict__ kw1,
                   float* __restrict__ biastot, float* __restrict__ tmp1) {
    const int idx = blockIdx.x * 256 + threadIdx.x;
    if (idx < 1024) {                       // tmp1: (16,64)
        const int b = idx >> 6, j = idx & 63;
        float s = 0.f;
        for (int e = 0; e < 64; ++e) s += kv[b * 64 + e] * kw1[j * 64 + e];
        tmp1[idx] = s >= 0.f ? s : NEG * s;
    } else if (idx < 1024 + 2048) {         // biastot: (16,128)
        const int t = idx - 1024;
        const int b = t >> 7, c = t & 127;
        float s = nfbias[c] + c1b[c];
        for (int e = 0; e < 128; ++e) s += te[b * 128 + e] * nfw[c * 128 + e];
        biastot[t] = s;
    }
}

__global__ __launch_bounds__(256)
void small2_kernel(const float* __restrict__ tmp1, const float* __restrict__ kw2,
                   float* __restrict__ kern) {
    const int idx = blockIdx.x * 256 + threadIdx.x;    // 18432
    if (idx < BB * CC * 9) {
        const int b = idx / 1152, rc = idx % 1152;
        float s = 0.f;
        for (int e = 0; e < 64; ++e) s += tmp1[b * 64 + e] * kw2[rc * 64 + e];
        kern[idx] = s;
    }
}

// ------- GroupNorm apply + Swish, NCHW fp32 -> NHWC bf16 (LDS transpose) ----
__global__ __launch_bounds__(256)
void gn_apply_kernel(const float* __restrict__ x, const float* __restrict__ gamma,
                     const float* __restrict__ beta, const float* __restrict__ stats,
                     u16* __restrict__ hact) {
    __shared__ u16 s_t[128 * 128];
    const int tid = threadIdx.x;
    const int y = blockIdx.x & 127, b = blockIdx.x >> 7;
    #pragma unroll
    for (int i = 0; i < 16; ++i) {
        int unit = (i << 8) + tid;              // (c, x-quad)
        int c = unit >> 5, xq = unit & 31, xx = xq * 4;
        float4 v = *(const float4*)&x[(((size_t)b * 128 + c) * 128 + y) * 128 + xx];
        int gi = b * 32 + (c >> 2);
        float mean = stats[2 * gi], rstd = stats[2 * gi + 1];
        float ga = gamma[c] * rstd, be = beta[c] - mean * ga;
        float a0 = v.x * ga + be, a1 = v.y * ga + be, a2 = v.z * ga + be, a3 = v.w * ga + be;
        a0 = a0 / (1.f + __expf(-a0)); a1 = a1 / (1.f + __expf(-a1));
        a2 = a2 / (1.f + __expf(-a2)); a3 = a3 / (1.f + __expf(-a3));
        int cs = c ^ ((xq & 15) << 3);          // bank swizzle, keeps 8-groups intact
        s_t[(xx + 0) * 128 + cs] = f2bf(a0);
        s_t[(xx + 1) * 128 + cs] = f2bf(a1);
        s_t[(xx + 2) * 128 + cs] = f2bf(a2);
        s_t[(xx + 3) * 128 + cs] = f2bf(a3);
    }
    __syncthreads();
    #pragma unroll
    for (int i = 0; i < 8; ++i) {
        int unit = (i << 8) + tid;              // (x, c-group)
        int xx = unit >> 4, c0 = (unit & 15) * 8;
        int c0s = c0 ^ (((xx >> 2) & 15) << 3);
        u16x8 v = *(const u16x8*)&s_t[xx * 128 + c0s];
        *(u16x8*)&hact[((((size_t)b * 128 + y) * 128 + xx) * 128) + c0] = v;
    }
}

// ---------------- MFMA implicit-GEMM 3x3 conv, 128->128, SAME --------------
// act: NHWC bf16. wt: [tap][chunk][g][co][8] bf16.
// 12 phases = 4 ci-chunks x 3 dy-rows. Weights staged per dy-row in LDS
// (double-buffered, one global->LDS latency per phase, amortized over 192
// block-MFMA). Act tile double-buffered per ci-chunk.
// FINAL=0: outh(NHWC bf16) = conv(act) + biastot[b][co]
// FINAL=1: outf(NCHW fp32) += conv(act) + bias[co]
template <int FINAL>
__global__ __launch_bounds__(256, 2)
void conv_mfma_kernel(const u16* __restrict__ act, const u16* __restrict__ wt,
                      const float* __restrict__ bias,
                      float* __restrict__ outf, u16* __restrict__ outh) {
    __shared__ __align__(16) u16 s_in[2][5760];    // [buf][cik(4)][pos(180)][8] = 23.0 KB
    __shared__ __align__(16) u16 s_w[2][12288];    // [buf][tapL(3)][g(4)][co(128)][8] = 49.2 KB

    const int tid = threadIdx.x;
    const int lane = tid & 63, wid = tid >> 6;
    const int wm = wid >> 1, wn = wid & 1;
    const int l15 = lane & 15, l4 = lane >> 4;

    // XCD-chunked swizzle: 2048 blocks -> each XCD gets 256 contiguous (2 images)
    const int bid0 = blockIdx.x;
    const int bid = ((bid0 & 7) << 8) | (bid0 >> 3);
    const int tx = bid & 7, ty = (bid >> 3) & 15, b = bid >> 7;
    const int x0 = tx * 16, y0 = ty * 8;
    const bool interior = (tx > 0) && (tx < 7) && (ty > 0) && (ty < 15);
    const size_t actbase = (size_t)b * (128 * 128 * 128);

    f32x4 acc[4][4];
    #pragma unroll
    for (int mi = 0; mi < 4; ++mi)
        #pragma unroll
        for (int nj = 0; nj < 4; ++nj) acc[mi][nj] = (f32x4)(0.f);

    auto stage_in = [&](int buf, int ci0) {
        #pragma unroll
        for (int r = 0; r < 3; ++r) {
            int L = r * 256 + tid;
            if (L < 720) {
                int cik = L / 180, rem = L % 180;
                int yy = rem / 18, xx = rem - yy * 18;
                int gy = y0 + yy - 1, gx = x0 + xx - 1;
                const u16* src = act + actbase + (((size_t)gy * 128 + gx) * 128 + ci0 + cik * 8);
                if (interior) {
                    u16* dst = &s_in[buf][(size_t)(r * 256 + ((tid >> 6) << 6)) * 8];
                    gload_lds16(src, dst);
                } else {
                    u16x8 v = (u16x8)(u16)0;
                    if ((unsigned)gy < 128u && (unsigned)gx < 128u) v = *(const u16x8*)src;
                    *(u16x8*)&s_in[buf][(size_t)L * 8] = v;
                }
            }
        }
    };
    // stage one dy-row of weights: [tapL(3)][g(4)][co(128)][8] = 24.6 KB
    auto stage_w = [&](int buf, int ck, int dyr) {
        #pragma unroll
        for (int rr = 0; rr < 6; ++rr) {
            int slot = rr * 256 + tid;              // 1536 slots of 16B
            int tapL = slot >> 9;
            int g    = (slot >> 7) & 3;
            int co   = slot & 127;
            const u16* src = wt + ((((size_t)(dyr * 3 + tapL) * 4 + ck) * 4 + g) * 128 + co) * 8;
            u16* dst = &s_w[buf][(size_t)(rr * 256 + ((tid >> 6) << 6)) * 8];
            gload_lds16(src, dst);
        }
    };

    stage_in(0, 0);
    stage_w(0, 0, 0);
    __syncthreads();

    // per-thread invariant offsets (u16 units)
    const int bbase  = (l4 * 180 + (wn * 4) * 18 + l15) * 8;       // act B-frag base
    const int awbase = (l4 * 128 + wm * 64 + l15) * 8;             // weight A-frag base

    int cur = 0;
    for (int chunk = 0; chunk < 4; ++chunk) {
        #pragma unroll
        for (int dyr = 0; dyr < 3; ++dyr) {
            const int p = chunk * 3 + dyr;
            // stage next phase's weights into the other buffer
            if (p + 1 < 12) {
                const int np = p + 1;
                stage_w(np & 1, np / 3, np % 3);
            }
            // act prefetch for next chunk (3 phases to land)
            if (dyr == 0 && chunk < 3) stage_in(cur ^ 1, (chunk + 1) * 32);

            const u16* sb  = &s_in[cur][0];
            const u16* swb = &s_w[p & 1][0];
            #pragma unroll
            for (int dx = 0; dx < 3; ++dx) {
                const int ao = awbase + dx * 4096;
                bfrag a0 = *(const bfrag*)&swb[ao];
                bfrag a1 = *(const bfrag*)&swb[ao + 128];
                bfrag a2 = *(const bfrag*)&swb[ao + 256];
                bfrag a3 = *(const bfrag*)&swb[ao + 384];
                const int bo = bbase + (dyr * 18 + dx) * 8;
                bfrag b0 = *(const bfrag*)&sb[bo];
                bfrag b1 = *(const bfrag*)&sb[bo + 144];
                bfrag b2 = *(const bfrag*)&sb[bo + 288];
                bfrag b3 = *(const bfrag*)&sb[bo + 432];

                acc[0][0] = __builtin_amdgcn_mfma_f32_16x16x32_bf16(a0, b0, acc[0][0], 0, 0, 0);
                acc[0][1] = __builtin_amdgcn_mfma_f32_16x16x32_bf16(a0, b1, acc[0][1], 0, 0, 0);
                acc[0][2] = __builtin_amdgcn_mfma_f32_16x16x32_bf16(a0, b2, acc[0][2], 0, 0, 0);
                acc[0][3] = __builtin_amdgcn_mfma_f32_16x16x32_bf16(a0, b3, acc[0][3], 0, 0, 0);
                acc[1][0] = __builtin_amdgcn_mfma_f32_16x16x32_bf16(a1, b0, acc[1][0], 0, 0, 0);
                acc[1][1] = __builtin_amdgcn_mfma_f32_16x16x32_bf16(a1, b1, acc[1][1], 0, 0, 0);
                acc[1][2] = __builtin_amdgcn_mfma_f32_16x16x32_bf16(a1, b2, acc[1][2], 0, 0, 0);
                acc[1][3] = __builtin_amdgcn_mfma_f32_16x16x32_bf16(a1, b3, acc[1][3], 0, 0, 0);
                acc[2][0] = __builtin_amdgcn_mfma_f32_16x16x32_bf16(a2, b0, acc[2][0], 0, 0, 0);
                acc[2][1] = __builtin_amdgcn_mfma_f32_16x16x32_bf16(a2, b1, acc[2][1], 0, 0, 0);
                acc[2][2] = __builtin_amdgcn_mfma_f32_16x16x32_bf16(a2, b2, acc[2][2], 0, 0, 0);
                acc[2][3] = __builtin_amdgcn_mfma_f32_16x16x32_bf16(a2, b3, acc[2][3], 0, 0, 0);
                acc[3][0] = __builtin_amdgcn_mfma_f32_16x16x32_bf16(a3, b0, acc[3][0], 0, 0, 0);
                acc[3][1] = __builtin_amdgcn_mfma_f32_16x16x32_bf16(a3, b1, acc[3][1], 0, 0, 0);
                acc[3][2] = __builtin_amdgcn_mfma_f32_16x16x32_bf16(a3, b2, acc[3][2], 0, 0, 0);
                acc[3][3] = __builtin_amdgcn_mfma_f32_16x16x32_bf16(a3, b3, acc[3][3], 0, 0, 0);
            }
            __syncthreads();   // next-phase W staged & visible; all readers done
        }
        cur ^= 1;
    }

    // ---- epilogue ----
    if (!FINAL) {
        const float* bb = bias + b * 128;
        #pragma unroll
        for (int mi = 0; mi < 4; ++mi) {
            const int cb = wm * 64 + mi * 16 + l4 * 4;
            float4 bv4 = *(const float4*)&bb[cb];
            #pragma unroll
            for (int nj = 0; nj < 4; ++nj) {
                int y = y0 + wn * 4 + nj, xx = x0 + l15;
                u16x4 p;
                p[0] = f2bf(acc[mi][nj][0] + bv4.x);
                p[1] = f2bf(acc[mi][nj][1] + bv4.y);
                p[2] = f2bf(acc[mi][nj][2] + bv4.z);
                p[3] = f2bf(acc[mi][nj][3] + bv4.w);
                *(u16x4*)&outh[((((size_t)b * 128 + y) * 128 + xx) * 128) + cb] = p;
            }
        }
    } else {
        #pragma unroll
        for (int mi = 0; mi < 4; ++mi) {
            const int cb = wm * 64 + mi * 16 + l4 * 4;
            float4 bv4 = *(const float4*)&bias[cb];
            #pragma unroll
            for (int nj = 0; nj < 4; ++nj) {
                int y = y0 + wn * 4 + nj, xx = x0 + l15;
                size_t obase = (((size_t)b * 128 + cb) * 128 + y) * 128 + xx;
                outf[obase]           += acc[mi][nj][0] + bv4.x;
                outf[obase + 16384]   += acc[mi][nj][1] + bv4.y;
                outf[obase + 32768]   += acc[mi][nj][2] + bv4.z;
                outf[obase + 49152]   += acc[mi][nj][3] + bv4.w;
            }
        }
    }
}

// ------- dynamic depthwise 3x3 + leaky + x residual -> out NCHW fp32 -------
__global__ __launch_bounds__(256)
void dw_kernel(const u16* __restrict__ hbuf, const float* __restrict__ kern,
               const float* __restrict__ xres, float* __restrict__ outf) {
    __shared__ float s_o[128][129];
    const int tid = threadIdx.x;
    const int y = blockIdx.x & 127, b = blockIdx.x >> 7;
    const int c0 = (tid & 15) * 8;

    float kreg[72];
    {
        const float* kp = kern + ((size_t)b * 128 + c0) * 9;
        #pragma unroll
        for (int t = 0; t < 18; ++t)
            *(float4*)&kreg[t * 4] = *(const float4*)&kp[t * 4];
    }

    #pragma unroll
    for (int i = 0; i < 8; ++i) {
        int u = (i << 8) + tid;
        int xx = u >> 4;
        float a8[8];
        #pragma unroll
        for (int e = 0; e < 8; ++e) a8[e] = 0.f;
        #pragma unroll
        for (int dy = 0; dy < 3; ++dy) {
            int gy = y + dy - 1;
            if ((unsigned)gy >= 128u) continue;
            #pragma unroll
            for (int dx = 0; dx < 3; ++dx) {
                int gx = xx + dx - 1;
                if ((unsigned)gx >= 128u) continue;
                u16x8 h = *(const u16x8*)&hbuf[(((size_t)b * 128 + gy) * 128 + gx) * 128 + c0];
                #pragma unroll
                for (int e = 0; e < 8; ++e)
                    a8[e] += bf2f(h[e]) * kreg[e * 9 + dy * 3 + dx];
            }
        }
        #pragma unroll
        for (int e = 0; e < 8; ++e) {
            float v = a8[e];
            s_o[c0 + e][xx] = v >= 0.f ? v : NEG * v;
        }
    }
    __syncthreads();
    #pragma unroll
    for (int i = 0; i < 16; ++i) {
        int unit = (i << 8) + tid;          // (c, x-quad)
        int c = unit >> 5, x4 = (unit & 31) * 4;
        float4 v = *(const float4*)&s_o[c][x4];
        size_t gi = (((size_t)b * 128 + c) * 128 + y) * 128 + x4;
        float4 xr = *(const float4*)&xres[gi];
        v.x += xr.x; v.y += xr.y; v.z += xr.z; v.w += xr.w;
        *(float4*)&outf[gi] = v;
    }
}

extern "C" void kernel_launch(void* const* d_in, const int* in_sizes, int n_in,
                              void* d_out, int out_size, void* d_ws, size_t ws_size,
                              hipStream_t stream) {
    const float* x        = (const float*)d_in[0];
    const float* te       = (const float*)d_in[1];
    const float* kv       = (const float*)d_in[2];
    const float* gn1_g    = (const float*)d_in[3];
    const float* gn1_b    = (const float*)d_in[4];
    const float* conv1_w  = (const float*)d_in[5];
    const float* conv1_b  = (const float*)d_in[6];
    const float* nf_w     = (const float*)d_in[7];
    const float* nf_b     = (const float*)d_in[8];
    const float* kW1      = (const float*)d_in[9];
    const float* kW2      = (const float*)d_in[10];
    const float* daconv_w = (const float*)d_in[11];
    const float* daconv_b = (const float*)d_in[12];

    float* out = (float*)d_out;

    // workspace (alive across the final kernels): kern, w2t, hbuf
    float* kern  = (float*)d_ws;                         // 18432 f32
    u16*   w2t   = (u16*)(kern + 18432);                 // 147456 u16
    u16*   hbuf  = (u16*)(kern + 92160);                 // 33.5M u16 (67 MB)

    // temps dead before dw_kernel overwrite of d_out: live in d_out upper half
    float* up      = out + 16777216;
    float* stats   = up;                                 // 1024
    float* biastot = up + 1024;                          // 2048
    float* tmp1    = up + 3072;                          // 1024
    u16*   w1t     = (u16*)(up + 4096);                  // 147456 u16
    u16*   hact    = (u16*)out;                          // lower half of d_out

    gn_stats_kernel<<<dim3(512), dim3(256), 0, stream>>>(x, stats);
    wconv_kernel<<<dim3(576), dim3(256), 0, stream>>>(conv1_w, daconv_w, w1t, w2t);
    small1_kernel<<<dim3(12), dim3(256), 0, stream>>>(te, nf_w, nf_b, conv1_b, kv, kW1,
                                                      biastot, tmp1);
    small2_kernel<<<dim3(72), dim3(256), 0, stream>>>(tmp1, kW2, kern);
    gn_apply_kernel<<<dim3(2048), dim3(256), 0, stream>>>(x, gn1_g, gn1_b, stats, hact);

    // conv1: hbuf = conv(hact) + biastot   (NHWC bf16)
    conv_mfma_kernel<0><<<dim3(2048), dim3(256), 0, stream>>>(hact, w1t, biastot, nullptr, hbuf);
    // dw: out = leaky(depthwise(hbuf, kern)) + x   (NCHW fp32, overwrites all of d_out)
    dw_kernel<<<dim3(2048), dim3(256), 0, stream>>>(hbuf, kern, x, out);
    // conv2: out += conv(hbuf) + daconv_b
    conv_mfma_kernel<1><<<dim3(2048), dim3(256), 0, stream>>>(hbuf, w2t, daconv_b, out, nullptr);
}